// Round 1
// baseline (1905.773 us; speedup 1.0000x reference)
//
#include <hip/hip_runtime.h>

// Problem dims (fixed by setup_inputs)
#define B_  4
#define L_  2048
#define D_  2048
#define R_  2560
#define BL_ (B_ * L_)

typedef unsigned short u16;
typedef unsigned int   u32;

typedef __attribute__((ext_vector_type(8))) short short8;
typedef __attribute__((ext_vector_type(4))) float f32x4;
typedef __attribute__((ext_vector_type(4))) int   int4v;

static __device__ __forceinline__ u16 f2bf(float f) {
  u32 x = __float_as_uint(f);
  x += 0x7fffu + ((x >> 16) & 1u);   // round-to-nearest-even
  return (u16)(x >> 16);
}
static __device__ __forceinline__ float bf2f(u16 u) {
  return __uint_as_float(((u32)u) << 16);
}

// ---------------- conversions ----------------
__global__ void cvt_bf16(const float* __restrict__ src, u16* __restrict__ dst, int n) {
  int i = blockIdx.x * blockDim.x + threadIdx.x;
  int stride = gridDim.x * blockDim.x;
  for (; i < n; i += stride) dst[i] = f2bf(src[i]);
}

// conv_w [R,R,4] fp32 -> 4 planes of [R,R] bf16 (tap-major)
__global__ void cvt_convw(const float* __restrict__ cw, u16* __restrict__ out) {
  int i = blockIdx.x * blockDim.x + threadIdx.x;  // over R_*R_ (o*R + iin)
  if (i >= R_ * R_) return;
  const float4 v = *(const float4*)(cw + (size_t)i * 4);
  out[(size_t)0 * R_ * R_ + i] = f2bf(v.x);
  out[(size_t)1 * R_ * R_ + i] = f2bf(v.y);
  out[(size_t)2 * R_ * R_ + i] = f2bf(v.z);
  out[(size_t)3 * R_ * R_ + i] = f2bf(v.w);
}

// ---------------- GEMM: C[M,N] = act(A[M,K] * Bm[N,K]^T + bias[N]) ----------------
// 128x128 block tile, BK=32, 256 threads = 4 waves in 2x2, each wave 64x64 (4x4 MFMA 16x16x32)
template <int ACT /*0=none,1=silu*/, int OBF16 /*1=bf16 out,0=f32 out*/>
__global__ __launch_bounds__(256)
void gemm_bt(const u16* __restrict__ A, const u16* __restrict__ Bm,
             const float* __restrict__ bias, void* __restrict__ Cv,
             int M, int N, int K) {
  __shared__ u16 As[128][40];  // +8 pad: row stride 80B -> <=2-way bank conflicts
  __shared__ u16 Bs[128][40];
  const int tid  = threadIdx.x;
  const int bm   = blockIdx.x * 128, bn = blockIdx.y * 128;
  const int wave = tid >> 6, lane = tid & 63;
  const int wm   = (wave >> 1) * 64, wn = (wave & 1) * 64;
  const int q    = lane >> 4, r16 = lane & 15;
  const int r0   = tid >> 2, c0 = (tid & 3) * 8;   // staging: 16B chunk per thread, x2 rows

  f32x4 acc[4][4] = {};

  const u16* aRow0 = A + (size_t)(bm + r0) * K + c0;
  const u16* aRow1 = A + (size_t)(bm + r0 + 64) * K + c0;
  const u16* bRow0 = Bm + (size_t)(bn + r0) * K + c0;
  const u16* bRow1 = Bm + (size_t)(bn + r0 + 64) * K + c0;

  for (int kk = 0; kk < K; kk += 32) {
    *(int4v*)(&As[r0][c0])      = *(const int4v*)(aRow0 + kk);
    *(int4v*)(&As[r0 + 64][c0]) = *(const int4v*)(aRow1 + kk);
    *(int4v*)(&Bs[r0][c0])      = *(const int4v*)(bRow0 + kk);
    *(int4v*)(&Bs[r0 + 64][c0]) = *(const int4v*)(bRow1 + kk);
    __syncthreads();
    short8 af[4], bfr[4];
#pragma unroll
    for (int i = 0; i < 4; ++i)
      af[i] = *(const short8*)(&As[wm + i * 16 + r16][q * 8]);
#pragma unroll
    for (int j = 0; j < 4; ++j)
      bfr[j] = *(const short8*)(&Bs[wn + j * 16 + r16][q * 8]);
#pragma unroll
    for (int i = 0; i < 4; ++i)
#pragma unroll
      for (int j = 0; j < 4; ++j)
        acc[i][j] = __builtin_amdgcn_mfma_f32_16x16x32_bf16(af[i], bfr[j], acc[i][j], 0, 0, 0);
    __syncthreads();
  }

#pragma unroll
  for (int i = 0; i < 4; ++i) {
    const int row = bm + wm + i * 16 + q * 4;
#pragma unroll
    for (int j = 0; j < 4; ++j) {
      const int col = bn + wn + j * 16 + r16;
      const float bv = bias[col];
#pragma unroll
      for (int rr = 0; rr < 4; ++rr) {
        float v = acc[i][j][rr] + bv;
        if (ACT == 1) v = v / (1.f + __expf(-v));
        const size_t off = (size_t)(row + rr) * N + col;
        if (OBF16) ((u16*)Cv)[off] = f2bf(v);
        else       ((float*)Cv)[off] = v;
      }
    }
  }
}

// ---------------- conv as 4 accumulated shifted GEMMs ----------------
// h2[bl,o] = conv_b[o] + sum_tap sum_i h1[bl + 2*tap - 3, i] * CW[tap][o][i]  (per-batch zero pad)
__global__ __launch_bounds__(256)
void conv_gemm(const u16* __restrict__ A, const u16* __restrict__ CW,
               const float* __restrict__ bias, u16* __restrict__ C) {
  __shared__ u16 As[128][40];
  __shared__ u16 Bs[128][40];
  const int tid  = threadIdx.x;
  const int bm   = blockIdx.x * 128, bn = blockIdx.y * 128;
  const int wave = tid >> 6, lane = tid & 63;
  const int wm   = (wave >> 1) * 64, wn = (wave & 1) * 64;
  const int q    = lane >> 4, r16 = lane & 15;
  const int r0   = tid >> 2, c0 = (tid & 3) * 8;

  f32x4 acc[4][4] = {};

  const int row0 = bm + r0, row1 = bm + r0 + 64;
  const int l0 = row0 & (L_ - 1), l1 = row1 & (L_ - 1);

  for (int tap = 0; tap < 4; ++tap) {
    const int sh = 2 * tap - 3;
    const bool v0 = (unsigned)(l0 + sh) < (unsigned)L_;
    const bool v1 = (unsigned)(l1 + sh) < (unsigned)L_;
    const u16* a0 = A + (size_t)(row0 + sh) * R_ + c0;
    const u16* a1 = A + (size_t)(row1 + sh) * R_ + c0;
    const u16* bp = CW + (size_t)tap * R_ * R_;
    const u16* b0 = bp + (size_t)(bn + r0) * R_ + c0;
    const u16* b1 = bp + (size_t)(bn + r0 + 64) * R_ + c0;
    const int4v zz = {0, 0, 0, 0};
    for (int kk = 0; kk < R_; kk += 32) {
      *(int4v*)(&As[r0][c0])      = v0 ? *(const int4v*)(a0 + kk) : zz;
      *(int4v*)(&As[r0 + 64][c0]) = v1 ? *(const int4v*)(a1 + kk) : zz;
      *(int4v*)(&Bs[r0][c0])      = *(const int4v*)(b0 + kk);
      *(int4v*)(&Bs[r0 + 64][c0]) = *(const int4v*)(b1 + kk);
      __syncthreads();
      short8 af[4], bfr[4];
#pragma unroll
      for (int i = 0; i < 4; ++i)
        af[i] = *(const short8*)(&As[wm + i * 16 + r16][q * 8]);
#pragma unroll
      for (int j = 0; j < 4; ++j)
        bfr[j] = *(const short8*)(&Bs[wn + j * 16 + r16][q * 8]);
#pragma unroll
      for (int i = 0; i < 4; ++i)
#pragma unroll
        for (int j = 0; j < 4; ++j)
          acc[i][j] = __builtin_amdgcn_mfma_f32_16x16x32_bf16(af[i], bfr[j], acc[i][j], 0, 0, 0);
      __syncthreads();
    }
  }

#pragma unroll
  for (int i = 0; i < 4; ++i) {
    const int row = bm + wm + i * 16 + q * 4;
#pragma unroll
    for (int j = 0; j < 4; ++j) {
      const int col = bn + wn + j * 16 + r16;
      const float bv = bias[col];
#pragma unroll
      for (int rr = 0; rr < 4; ++rr) {
        float v = acc[i][j][rr] + bv;
        C[(size_t)(row + rr) * R_ + col] = f2bf(v);
      }
    }
  }
}

// ---------------- RG-LRU elementwise: build (a, b) fp32 ----------------
__global__ void gate_ew(const u16* __restrict__ gab, const u16* __restrict__ gib,
                        const u16* __restrict__ h2b, const float* __restrict__ lam,
                        float* __restrict__ a32, float* __restrict__ b32) {
  int idx = blockIdx.x * blockDim.x + threadIdx.x;
  if (idx >= BL_ * R_) return;
  const int r = idx % R_;
  const float ga = bf2f(gab[idx]);
  const float gi = bf2f(gib[idx]);
  const float h2 = bf2f(h2b[idx]);
  const float rr = 1.f / (1.f + __expf(-ga));
  const float ii = 1.f / (1.f + __expf(-gi));
  const float lm = lam[r];
  const float sp = log1pf(__expf(lm));          // softplus, lam in [0.5,2]
  const float log_a = -8.f * rr * sp;
  const float a  = __expf(log_a);
  const float e2 = __expf(2.f * log_a);
  const float mult = sqrtf(fmaxf(1.f - e2, 0.f));
  a32[idx] = a;
  b32[idx] = mult * ii * h2;
}

// ---------------- sequential scan along L, one thread per (b, r) ----------------
__global__ void scan_k(const float* __restrict__ a32, const float* __restrict__ b32,
                       u16* __restrict__ hs) {
  int t = blockIdx.x * blockDim.x + threadIdx.x;
  if (t >= B_ * R_) return;
  const int b = t / R_, r = t % R_;
  size_t idx = (size_t)b * L_ * R_ + r;
  float h = 0.f;
  for (int l = 0; l < L_; ++l) {
    h = a32[idx] * h + b32[idx];
    hs[idx] = f2bf(h);
    idx += R_;
  }
}

// ---------------- launcher ----------------
extern "C" void kernel_launch(void* const* d_in, const int* in_sizes, int n_in,
                              void* d_out, int out_size, void* d_ws, size_t ws_size,
                              hipStream_t stream) {
  (void)in_sizes; (void)n_in; (void)out_size; (void)ws_size;
  const float* x   = (const float*)d_in[0];
  const float* w1  = (const float*)d_in[1];
  const float* b1  = (const float*)d_in[2];
  const float* cw  = (const float*)d_in[3];
  const float* cb  = (const float*)d_in[4];
  const float* wa  = (const float*)d_in[5];
  const float* ba  = (const float*)d_in[6];
  const float* wx  = (const float*)d_in[7];
  const float* bx  = (const float*)d_in[8];
  const float* lam = (const float*)d_in[9];
  const float* w2  = (const float*)d_in[10];
  const float* b2  = (const float*)d_in[11];

  char* ws = (char*)d_ws;
  size_t o = 0;
  auto alloc = [&](size_t bytes) { char* p = ws + o; o += (bytes + 255) & ~255ull; return p; };

  u16* w2b = (u16*)alloc((size_t)D_ * R_ * 2);
  u16* wab = (u16*)alloc((size_t)R_ * R_ * 2);
  u16* wxb = (u16*)alloc((size_t)R_ * R_ * 2);
  char* a32p = ws + o;                       // overlay: xb+w1b+cwb (dead by then) = 96.5MB >= 84MB
  u16* xb  = (u16*)alloc((size_t)BL_ * D_ * 2);
  u16* w1b = (u16*)alloc((size_t)R_ * D_ * 2);
  u16* cwb = (u16*)alloc((size_t)4 * R_ * R_ * 2);
  char* b32p = ws + o;                       // overlay: h1b (dead) + extra = 84MB
  u16* h1b = (u16*)alloc((size_t)BL_ * R_ * 2);
  alloc((size_t)BL_ * R_ * 2);               // extra half of b32 overlay
  u16* h2b = (u16*)alloc((size_t)BL_ * R_ * 2);
  u16* gab = (u16*)alloc((size_t)BL_ * R_ * 2);
  u16* gib = (u16*)alloc((size_t)BL_ * R_ * 2);
  float* a32 = (float*)a32p;
  float* b32 = (float*)b32p;
  u16* hsb = gab;                            // reuse after gate_ew consumed it

  cvt_bf16<<<4096, 256, 0, stream>>>(x,  xb,  BL_ * D_);
  cvt_bf16<<<2048, 256, 0, stream>>>(w1, w1b, R_ * D_);
  cvt_bf16<<<2048, 256, 0, stream>>>(wa, wab, R_ * R_);
  cvt_bf16<<<2048, 256, 0, stream>>>(wx, wxb, R_ * R_);
  cvt_bf16<<<2048, 256, 0, stream>>>(w2, w2b, D_ * R_);
  cvt_convw<<<(R_ * R_ + 255) / 256, 256, 0, stream>>>(cw, cwb);

  // linear1 + silu
  gemm_bt<1, 1><<<dim3(BL_ / 128, R_ / 128), 256, 0, stream>>>(xb, w1b, b1, h1b, BL_, R_, D_);
  // temporal conv (4 shifted GEMMs)
  conv_gemm<<<dim3(BL_ / 128, R_ / 128), 256, 0, stream>>>(h1b, cwb, cb, h2b);
  // gates
  gemm_bt<0, 1><<<dim3(BL_ / 128, R_ / 128), 256, 0, stream>>>(h2b, wab, ba, gab, BL_, R_, R_);
  gemm_bt<0, 1><<<dim3(BL_ / 128, R_ / 128), 256, 0, stream>>>(h2b, wxb, bx, gib, BL_, R_, R_);
  // a,b for recurrence
  gate_ew<<<(BL_ * R_ + 255) / 256, 256, 0, stream>>>(gab, gib, h2b, lam, a32, b32);
  // linear recurrence
  scan_k<<<(B_ * R_ + 255) / 256, 256, 0, stream>>>(a32, b32, hsb);
  // linear2 -> d_out (fp32)
  gemm_bt<0, 0><<<dim3(BL_ / 128, D_ / 128), 256, 0, stream>>>(hsb, w2b, b2, d_out, BL_, D_, R_);
}

// Round 2
// 1643.208 us; speedup vs baseline: 1.1598x; 1.1598x over previous
//
#include <hip/hip_runtime.h>

// Problem dims (fixed by setup_inputs)
#define B_  4
#define L_  2048
#define D_  2048
#define R_  2560
#define BL_ (B_ * L_)

#define CHK_  16            // scan chunks along L
#define CLEN_ (L_ / CHK_)   // 128

typedef unsigned short u16;
typedef unsigned int   u32;

typedef __attribute__((ext_vector_type(8))) short short8;
typedef __attribute__((ext_vector_type(4))) float f32x4;
typedef __attribute__((ext_vector_type(4))) int   int4v;

static __device__ __forceinline__ u16 f2bf(float f) {
  u32 x = __float_as_uint(f);
  x += 0x7fffu + ((x >> 16) & 1u);   // round-to-nearest-even
  return (u16)(x >> 16);
}
static __device__ __forceinline__ float bf2f(u16 u) {
  return __uint_as_float(((u32)u) << 16);
}

// async global->LDS, 16B per lane; LDS dest = wave-uniform base + lane*16
static __device__ __forceinline__ void gld16(const u16* g, u16* l) {
  __builtin_amdgcn_global_load_lds(
      (const __attribute__((address_space(1))) void*)g,
      (__attribute__((address_space(3))) void*)l, 16, 0, 0);
}

// ---------------- conversions ----------------
__global__ void cvt_bf16(const float* __restrict__ src, u16* __restrict__ dst, int n) {
  int i = blockIdx.x * blockDim.x + threadIdx.x;
  int stride = gridDim.x * blockDim.x;
  for (; i < n; i += stride) dst[i] = f2bf(src[i]);
}

// conv_w [R,R,4] fp32 -> 4 planes of [R,R] bf16 (tap-major)
__global__ void cvt_convw(const float* __restrict__ cw, u16* __restrict__ out) {
  int i = blockIdx.x * blockDim.x + threadIdx.x;  // over R_*R_ (o*R + iin)
  if (i >= R_ * R_) return;
  const float4 v = *(const float4*)(cw + (size_t)i * 4);
  out[(size_t)0 * R_ * R_ + i] = f2bf(v.x);
  out[(size_t)1 * R_ * R_ + i] = f2bf(v.y);
  out[(size_t)2 * R_ * R_ + i] = f2bf(v.z);
  out[(size_t)3 * R_ * R_ + i] = f2bf(v.w);
}

// ---------------- GEMM: C[M,N] = act(A[M,K] * Bm[N,K]^T + bias[N]) ----------------
// 128x128 block tile, BK=32, 256 threads = 4 waves 2x2, each wave 64x64 (4x4 MFMA 16x16x32).
// LDS: unpadded [128][32] u16, 64B row stride; chunk swizzle c ^ (row&3) -> conflict-free
// fragment reads AND satisfies global_load_lds's "base + lane*16" dest constraint.
template <int ACT /*0=none,1=silu*/, int OBF16 /*1=bf16 out,0=f32 out*/>
__global__ __launch_bounds__(256)
void gemm_bt(const u16* __restrict__ A, const u16* __restrict__ Bm,
             const float* __restrict__ bias, void* __restrict__ Cv,
             int M, int N, int K) {
  __shared__ u16 As[128 * 32];
  __shared__ u16 Bs[128 * 32];
  const int tid  = threadIdx.x;
  const int bm   = blockIdx.x * 128, bn = blockIdx.y * 128;
  const int wave = tid >> 6, lane = tid & 63;
  const int wm   = (wave >> 1) * 64, wn = (wave & 1) * 64;
  const int q    = lane >> 4, r16 = lane & 15;
  const int lrow = lane >> 2;                 // 0..15 within a 16-row group
  const int gch  = (lane & 3) ^ (lrow & 3);   // swizzled global chunk this lane fetches

  f32x4 acc[4][4] = {};

  const int swz = (q ^ (r16 & 3)) * 8;        // fragment read chunk offset (u16 elems)

  for (int kk = 0; kk < K; kk += 32) {
#pragma unroll
    for (int p = 0; p < 2; ++p) {
      const int rb = wave * 32 + p * 16;      // wave-uniform row base of 16-row group
      gld16(A  + (size_t)(bm + rb + lrow) * K + kk + gch * 8, &As[rb * 32]);
      gld16(Bm + (size_t)(bn + rb + lrow) * K + kk + gch * 8, &Bs[rb * 32]);
    }
    __syncthreads();
    short8 af[4], bfr[4];
#pragma unroll
    for (int i = 0; i < 4; ++i)
      af[i] = *(const short8*)(&As[(wm + i * 16 + r16) * 32 + swz]);
#pragma unroll
    for (int j = 0; j < 4; ++j)
      bfr[j] = *(const short8*)(&Bs[(wn + j * 16 + r16) * 32 + swz]);
#pragma unroll
    for (int i = 0; i < 4; ++i)
#pragma unroll
      for (int j = 0; j < 4; ++j)
        acc[i][j] = __builtin_amdgcn_mfma_f32_16x16x32_bf16(af[i], bfr[j], acc[i][j], 0, 0, 0);
    __syncthreads();
  }

#pragma unroll
  for (int i = 0; i < 4; ++i) {
    const int row = bm + wm + i * 16 + q * 4;
#pragma unroll
    for (int j = 0; j < 4; ++j) {
      const int col = bn + wn + j * 16 + r16;
      const float bv = bias[col];
#pragma unroll
      for (int rr = 0; rr < 4; ++rr) {
        float v = acc[i][j][rr] + bv;
        if (ACT == 1) v = v / (1.f + __expf(-v));
        const size_t off = (size_t)(row + rr) * N + col;
        if (OBF16) ((u16*)Cv)[off] = f2bf(v);
        else       ((float*)Cv)[off] = v;
      }
    }
  }
}

// ---------------- conv as 4 accumulated shifted GEMMs ----------------
// h2[bl,o] = conv_b[o] + sum_tap sum_i h1[bl + 2*tap - 3, i] * CW[tap][o][i]  (per-batch zero pad)
__global__ __launch_bounds__(256)
void conv_gemm(const u16* __restrict__ A, const u16* __restrict__ CW,
               const float* __restrict__ bias, u16* __restrict__ C) {
  __shared__ u16 As[128 * 32];
  __shared__ u16 Bs[128 * 32];
  const int tid  = threadIdx.x;
  const int bm   = blockIdx.x * 128, bn = blockIdx.y * 128;
  const int wave = tid >> 6, lane = tid & 63;
  const int wm   = (wave >> 1) * 64, wn = (wave & 1) * 64;
  const int q    = lane >> 4, r16 = lane & 15;
  const int lrow = lane >> 2;
  const int gch  = (lane & 3) ^ (lrow & 3);
  const int swz  = (q ^ (r16 & 3)) * 8;
  // fallback-staging indices (predicated boundary path)
  const int r0 = tid >> 2, c0g = (tid & 3) * 8;
  const int dsw0 = ((tid & 3) ^ (r0 & 3)) * 8;
  const int l0 = (bm + r0) & (L_ - 1), l1 = (bm + r0 + 64) & (L_ - 1);
  const int tileL = blockIdx.x & 15;          // tile index within a batch (16 tiles of 128)

  f32x4 acc[4][4] = {};

  for (int tap = 0; tap < 4; ++tap) {
    const int sh = 2 * tap - 3;
    // rows of this tile all valid for this tap unless at a batch boundary tile
    const bool safe = (sh < 0) ? (tileL != 0) : (tileL != 15);
    const bool v0 = (unsigned)(l0 + sh) < (unsigned)L_;
    const bool v1 = (unsigned)(l1 + sh) < (unsigned)L_;
    const u16* aSh = A + (ptrdiff_t)(bm + sh) * R_;
    const u16* bp  = CW + (size_t)tap * R_ * R_;
    const int4v zz = {0, 0, 0, 0};
    for (int kk = 0; kk < R_; kk += 32) {
#pragma unroll
      for (int p = 0; p < 2; ++p) {
        const int rb = wave * 32 + p * 16;
        gld16(bp + (size_t)(bn + rb + lrow) * R_ + kk + gch * 8, &Bs[rb * 32]);
      }
      if (safe) {
#pragma unroll
        for (int p = 0; p < 2; ++p) {
          const int rb = wave * 32 + p * 16;
          gld16(aSh + (size_t)(rb + lrow) * R_ + kk + gch * 8, &As[rb * 32]);
        }
      } else {
        *(int4v*)(&As[r0 * 32 + dsw0]) =
            v0 ? *(const int4v*)(aSh + (size_t)r0 * R_ + kk + c0g) : zz;
        *(int4v*)(&As[(r0 + 64) * 32 + dsw0]) =
            v1 ? *(const int4v*)(aSh + (size_t)(r0 + 64) * R_ + kk + c0g) : zz;
      }
      __syncthreads();
      short8 af[4], bfr[4];
#pragma unroll
      for (int i = 0; i < 4; ++i)
        af[i] = *(const short8*)(&As[(wm + i * 16 + r16) * 32 + swz]);
#pragma unroll
      for (int j = 0; j < 4; ++j)
        bfr[j] = *(const short8*)(&Bs[(wn + j * 16 + r16) * 32 + swz]);
#pragma unroll
      for (int i = 0; i < 4; ++i)
#pragma unroll
        for (int j = 0; j < 4; ++j)
          acc[i][j] = __builtin_amdgcn_mfma_f32_16x16x32_bf16(af[i], bfr[j], acc[i][j], 0, 0, 0);
      __syncthreads();
    }
  }

#pragma unroll
  for (int i = 0; i < 4; ++i) {
    const int row = bm + wm + i * 16 + q * 4;
#pragma unroll
    for (int j = 0; j < 4; ++j) {
      const int col = bn + wn + j * 16 + r16;
      const float bv = bias[col];
#pragma unroll
      for (int rr = 0; rr < 4; ++rr) {
        float v = acc[i][j][rr] + bv;
        C[(size_t)(row + rr) * R_ + col] = f2bf(v);
      }
    }
  }
}

// ---------------- RG-LRU elementwise: build (a, b) fp32 ----------------
__global__ void gate_ew(const u16* __restrict__ gab, const u16* __restrict__ gib,
                        const u16* __restrict__ h2b, const float* __restrict__ lam,
                        float* __restrict__ a32, float* __restrict__ b32) {
  int idx = blockIdx.x * blockDim.x + threadIdx.x;
  if (idx >= BL_ * R_) return;
  const int r = idx % R_;
  const float ga = bf2f(gab[idx]);
  const float gi = bf2f(gib[idx]);
  const float h2 = bf2f(h2b[idx]);
  const float rr = 1.f / (1.f + __expf(-ga));
  const float ii = 1.f / (1.f + __expf(-gi));
  const float lm = lam[r];
  const float sp = log1pf(__expf(lm));          // softplus, lam in [0.5,2]
  const float log_a = -8.f * rr * sp;
  const float a  = __expf(log_a);
  const float e2 = __expf(2.f * log_a);
  const float mult = sqrtf(fmaxf(1.f - e2, 0.f));
  a32[idx] = a;
  b32[idx] = mult * ii * h2;
}

// ---------------- chunked scan: 3 passes ----------------
__global__ void scan_pass1(const float* __restrict__ a32, const float* __restrict__ b32,
                           float* __restrict__ Aprod, float* __restrict__ Hend) {
  int t = blockIdx.x * blockDim.x + threadIdx.x;   // over CHK_*B_*R_
  if (t >= CHK_ * B_ * R_) return;
  const int c = t / (B_ * R_), br = t % (B_ * R_);
  const int b = br / R_, r = br % R_;
  size_t idx = ((size_t)b * L_ + c * CLEN_) * R_ + r;
  float Ap = 1.f, h = 0.f;
  for (int l = 0; l < CLEN_; ++l) {
    const float a = a32[idx], bb = b32[idx];
    Ap *= a;
    h = a * h + bb;
    idx += R_;
  }
  Aprod[t] = Ap;
  Hend[t]  = h;
}

__global__ void scan_pass2(const float* __restrict__ Aprod, float* __restrict__ Hend) {
  int br = blockIdx.x * blockDim.x + threadIdx.x;
  if (br >= B_ * R_) return;
  float h = Hend[br];                               // chunk 0 end state
  for (int c = 1; c < CHK_; ++c) {
    const int i = c * (B_ * R_) + br;
    h = Hend[i] + Aprod[i] * h;
    Hend[i] = h;
  }
}

__global__ void scan_pass3(const float* __restrict__ a32, const float* __restrict__ b32,
                           const float* __restrict__ Hend, u16* __restrict__ hs) {
  int t = blockIdx.x * blockDim.x + threadIdx.x;
  if (t >= CHK_ * B_ * R_) return;
  const int c = t / (B_ * R_), br = t % (B_ * R_);
  const int b = br / R_, r = br % R_;
  float h = (c == 0) ? 0.f : Hend[(size_t)(c - 1) * (B_ * R_) + br];
  size_t idx = ((size_t)b * L_ + c * CLEN_) * R_ + r;
  for (int l = 0; l < CLEN_; ++l) {
    h = a32[idx] * h + b32[idx];
    hs[idx] = f2bf(h);
    idx += R_;
  }
}

// ---------------- launcher ----------------
extern "C" void kernel_launch(void* const* d_in, const int* in_sizes, int n_in,
                              void* d_out, int out_size, void* d_ws, size_t ws_size,
                              hipStream_t stream) {
  (void)in_sizes; (void)n_in; (void)out_size; (void)ws_size;
  const float* x   = (const float*)d_in[0];
  const float* w1  = (const float*)d_in[1];
  const float* b1  = (const float*)d_in[2];
  const float* cw  = (const float*)d_in[3];
  const float* cb  = (const float*)d_in[4];
  const float* wa  = (const float*)d_in[5];
  const float* ba  = (const float*)d_in[6];
  const float* wx  = (const float*)d_in[7];
  const float* bx  = (const float*)d_in[8];
  const float* lam = (const float*)d_in[9];
  const float* w2  = (const float*)d_in[10];
  const float* b2  = (const float*)d_in[11];

  char* ws = (char*)d_ws;
  size_t o = 0;
  auto alloc = [&](size_t bytes) { char* p = ws + o; o += (bytes + 255) & ~255ull; return p; };

  u16* w2b = (u16*)alloc((size_t)D_ * R_ * 2);
  u16* wab = (u16*)alloc((size_t)R_ * R_ * 2);
  u16* wxb = (u16*)alloc((size_t)R_ * R_ * 2);
  char* a32p = ws + o;                       // overlay: xb+w1b+cwb (dead by then) = 96.5MB >= 84MB
  u16* xb  = (u16*)alloc((size_t)BL_ * D_ * 2);
  u16* w1b = (u16*)alloc((size_t)R_ * D_ * 2);
  u16* cwb = (u16*)alloc((size_t)4 * R_ * R_ * 2);
  char* b32p = ws + o;                       // overlay: h1b (dead) + extra = 84MB
  u16* h1b = (u16*)alloc((size_t)BL_ * R_ * 2);
  alloc((size_t)BL_ * R_ * 2);               // extra half of b32 overlay
  u16* h2b = (u16*)alloc((size_t)BL_ * R_ * 2);
  u16* gab = (u16*)alloc((size_t)BL_ * R_ * 2);
  u16* gib = (u16*)alloc((size_t)BL_ * R_ * 2);
  float* Aprod = (float*)alloc((size_t)CHK_ * B_ * R_ * 4);
  float* Hend  = (float*)alloc((size_t)CHK_ * B_ * R_ * 4);
  float* a32 = (float*)a32p;
  float* b32 = (float*)b32p;
  u16* hsb = gab;                            // reuse after gate_ew consumed it

  cvt_bf16<<<4096, 256, 0, stream>>>(x,  xb,  BL_ * D_);
  cvt_bf16<<<2048, 256, 0, stream>>>(w1, w1b, R_ * D_);
  cvt_bf16<<<2048, 256, 0, stream>>>(wa, wab, R_ * R_);
  cvt_bf16<<<2048, 256, 0, stream>>>(wx, wxb, R_ * R_);
  cvt_bf16<<<2048, 256, 0, stream>>>(w2, w2b, D_ * R_);
  cvt_convw<<<(R_ * R_ + 255) / 256, 256, 0, stream>>>(cw, cwb);

  // linear1 + silu
  gemm_bt<1, 1><<<dim3(BL_ / 128, R_ / 128), 256, 0, stream>>>(xb, w1b, b1, h1b, BL_, R_, D_);
  // temporal conv (4 shifted GEMMs)
  conv_gemm<<<dim3(BL_ / 128, R_ / 128), 256, 0, stream>>>(h1b, cwb, cb, h2b);
  // gates
  gemm_bt<0, 1><<<dim3(BL_ / 128, R_ / 128), 256, 0, stream>>>(h2b, wab, ba, gab, BL_, R_, R_);
  gemm_bt<0, 1><<<dim3(BL_ / 128, R_ / 128), 256, 0, stream>>>(h2b, wxb, bx, gib, BL_, R_, R_);
  // a,b for recurrence
  gate_ew<<<(BL_ * R_ + 255) / 256, 256, 0, stream>>>(gab, gib, h2b, lam, a32, b32);
  // linear recurrence (chunked, 3 passes)
  scan_pass1<<<(CHK_ * B_ * R_ + 255) / 256, 256, 0, stream>>>(a32, b32, Aprod, Hend);
  scan_pass2<<<(B_ * R_ + 255) / 256, 256, 0, stream>>>(Aprod, Hend);
  scan_pass3<<<(CHK_ * B_ * R_ + 255) / 256, 256, 0, stream>>>(a32, b32, Hend, hsb);
  // linear2 -> d_out (fp32)
  gemm_bt<0, 0><<<dim3(BL_ / 128, D_ / 128), 256, 0, stream>>>(hsb, w2b, b2, d_out, BL_, D_, R_);
}